// Round 10
// baseline (153.168 us; speedup 1.0000x reference)
//
#include <hip/hip_runtime.h>
#include <hip/hip_bf16.h>
#include <math.h>

#define B_   32
#define J_   1182      // V*P = 6*197
#define D_   512
#define L_   77
#define C_   5
#define JCA_ 16        // j-chunk for fused attention
#define NCHA_ 74       // ceil(1182/16)

__device__ __forceinline__ float dot4(float4 a, float4 b) {
    return a.x*b.x + a.y*b.y + a.z*b.z + a.w*b.w;
}

__device__ __forceinline__ float wave_sum(float v) {
#pragma unroll
    for (int off = 32; off > 0; off >>= 1) v += __shfl_xor(v, off, 64);
    return v;
}

// K1: blocks 0..1371: cond_maps (o-major, wave per o, 5 conditions per weight read)
//     block 1372: fn normalize -> fn global + loss_dis -> loss_out
__global__ void k_setup(const float* __restrict__ fc, const float* __restrict__ cw,
                        const float* __restrict__ cb, float* __restrict__ cm,
                        float* __restrict__ fn, float* __restrict__ loss_out) {
    __shared__ float sfc[C_*D_];
    int t = threadIdx.x;
    for (int i = t; i < C_*D_; i += 256) sfc[i] = fc[i];
    __syncthreads();
    int wave = t >> 6, lane = t & 63;

    if (blockIdx.x == 1372) {
        for (int c = wave; c < C_; c += 4) {
            float ss = 0.f;
            for (int d = lane; d < D_; d += 64) { float v = sfc[c*D_+d]; ss += v*v; }
            ss = wave_sum(ss);
            float inv = 1.f / fmaxf(sqrtf(ss), 1e-12f);
            for (int d = lane; d < D_; d += 64) sfc[c*D_+d] *= inv;
        }
        __syncthreads();
        for (int i = t; i < C_*D_; i += 256) fn[i] = sfc[i];
        if (wave == 0) {
            float acc = 0.f;
            for (int i = 0; i < C_; ++i)
                for (int j = i+1; j < C_; ++j) {
                    float p = 0.f;
                    for (int d = lane; d < D_; d += 64) p += sfc[i*D_+d]*sfc[j*D_+d];
                    p = wave_sum(p);
                    acc += fmaxf(p, 0.f);
                }
            if (lane == 0) *loss_out = acc * (1.f/10.f);
        }
        return;
    }

    int o = blockIdx.x*4 + wave;         // < 5488
    const float4* w4 = (const float4*)(cw + (size_t)o*D_);
    float4 wa = w4[lane], wb = w4[lane+64];
    float bias = cb[o];
    float keep = 0.f;
#pragma unroll
    for (int c = 0; c < C_; ++c) {
        const float4* f4 = (const float4*)(sfc + c*D_);
        float s = dot4(wa, f4[lane]) + dot4(wb, f4[lane+64]);
        s = wave_sum(s);
        if (lane == c) keep = s;
    }
    if (lane < C_) cm[lane*5488 + o] = keep + bias;
}

// K2: 8 threads per (b,l) row (seg of 64 floats each), 3-level shuffle reduce.
// swl[b,c,l] = (fp[b,l]·fn[c]) / ||fp[b,l]||^2
__global__ void k_sim(const float* __restrict__ fp, const float* __restrict__ fn,
                      float* __restrict__ swl) {
    int t = threadIdx.x;                 // 256 -> 32 rows/block
    int row = t >> 3, seg = t & 7;
    int bl = blockIdx.x*32 + row;        // grid 77 -> exactly 2464 rows
    int b = bl / L_, l = bl - b*L_;
    const float4* p4 = ((const float4*)(fp + (size_t)bl*D_)) + seg*16;
    const float4* f4 = ((const float4*)fn) + seg*16;   // [c*128 + k]
    float ss=0.f, s0=0.f, s1=0.f, s2=0.f, s3=0.f, s4=0.f;
#pragma unroll 4
    for (int k = 0; k < 16; ++k) {
        float4 v = p4[k];
        ss += dot4(v, v);
        s0 += dot4(v, f4[k]);
        s1 += dot4(v, f4[128+k]);
        s2 += dot4(v, f4[256+k]);
        s3 += dot4(v, f4[384+k]);
        s4 += dot4(v, f4[512+k]);
    }
#pragma unroll
    for (int off = 1; off < 8; off <<= 1) {
        ss += __shfl_xor(ss,off,64);
        s0 += __shfl_xor(s0,off,64); s1 += __shfl_xor(s1,off,64);
        s2 += __shfl_xor(s2,off,64); s3 += __shfl_xor(s3,off,64);
        s4 += __shfl_xor(s4,off,64);
    }
    if (seg == 0) {
        float inv = 1.f / fmaxf(sqrtf(ss), 1e-12f);
        float inv2 = inv*inv;
        swl[((size_t)(b*C_+0))*L_ + l] = s0*inv2;
        swl[((size_t)(b*C_+1))*L_ + l] = s1*inv2;
        swl[((size_t)(b*C_+2))*L_ + l] = s2*inv2;
        swl[((size_t)(b*C_+3))*L_ + l] = s3*inv2;
        swl[((size_t)(b*C_+4))*L_ + l] = s4*inv2;
    }
}

// K3: Q[b,c,d] = sum_l swl[b,c,l] * fp[b,l,d]   grid (2, B_), 256 thr, d per thread
__global__ void k_Q(const float* __restrict__ fp, const float* __restrict__ swl,
                    float* __restrict__ Q) {
    __shared__ float sw[C_][80];
    int b = blockIdx.y;
    int t = threadIdx.x;
    for (int i = t; i < C_*L_; i += 256) { int c = i/L_, l = i - c*L_; sw[c][l] = swl[((size_t)(b*C_+c))*L_ + l]; }
    __syncthreads();
    int d = blockIdx.x*256 + t;
    float a0=0.f, a1=0.f, a2=0.f, a3=0.f, a4=0.f;
    const float* f = fp + (size_t)b*L_*D_ + d;
    for (int l = 0; l < L_; ++l) {
        float v = f[(size_t)l*D_];
        a0 += sw[0][l]*v; a1 += sw[1][l]*v; a2 += sw[2][l]*v;
        a3 += sw[3][l]*v; a4 += sw[4][l]*v;
    }
    Q[(size_t)(b*C_+0)*D_ + d] = a0;
    Q[(size_t)(b*C_+1)*D_ + d] = a1;
    Q[(size_t)(b*C_+2)*D_ + d] = a2;
    Q[(size_t)(b*C_+3)*D_ + d] = a3;
    Q[(size_t)(b*C_+4)*D_ + d] = a4;
}

// K4: fused single-pass attention over tex. 256 thr, grid (NCHA_, B_).
// LDS layout (padded): row stride 576 words; float4 col4 -> word 4*col4 + 4*(col4>>3).
__global__ void k_attn(const float* __restrict__ tex, const float* __restrict__ Q,
                       float* __restrict__ part, float2* __restrict__ msum) {
    __shared__ float stex[JCA_*576];     // 36864 B
    __shared__ float sq[C_*576];         // 11520 B
    __shared__ float srawT[JCA_][8];
    int chunk = blockIdx.x, b = blockIdx.y;
    int t = threadIdx.x;                 // 256
    int j0 = chunk*JCA_;
    int jn = min(JCA_, J_ - j0);

    // phase 0: coalesced staging
    {
        const float4* q4 = (const float4*)(Q + (size_t)b*C_*D_);   // 640 float4
        for (int i = t; i < C_*128; i += 256) {
            int c = i >> 7, col4 = i & 127;
            *(float4*)(sq + c*576 + col4*4 + ((col4>>3)<<2)) = q4[i];
        }
        const float4* t4 = (const float4*)(tex + ((size_t)(b*J_ + j0))*D_);
#pragma unroll
        for (int n = 0; n < 8; ++n) {
            int i = n*256 + t;           // < 2048
            int row = i >> 7, col4 = i & 127;
            if (row < jn)
                *(float4*)(stex + row*576 + col4*4 + ((col4>>3)<<2)) = t4[i];
        }
    }
    __syncthreads();

    // phase 1: scores from LDS
    {
        int row = t >> 4, seg = t & 15;
        const float* sr = stex + row*576;
        float ss=0.f, s0=0.f, s1=0.f, s2=0.f, s3=0.f, s4=0.f;
#pragma unroll
        for (int k = 0; k < 8; ++k) {
            int col4 = seg*8 + k;
            int wa = col4*4 + ((col4>>3)<<2);
            float4 v = *(const float4*)(sr + wa);
            ss += dot4(v, v);
            s0 += dot4(v, *(const float4*)(sq +          wa));
            s1 += dot4(v, *(const float4*)(sq +   576 + wa));
            s2 += dot4(v, *(const float4*)(sq + 2*576 + wa));
            s3 += dot4(v, *(const float4*)(sq + 3*576 + wa));
            s4 += dot4(v, *(const float4*)(sq + 4*576 + wa));
        }
#pragma unroll
        for (int off = 1; off < 16; off <<= 1) {
            ss += __shfl_xor(ss,off,64);
            s0 += __shfl_xor(s0,off,64); s1 += __shfl_xor(s1,off,64);
            s2 += __shfl_xor(s2,off,64); s3 += __shfl_xor(s3,off,64);
            s4 += __shfl_xor(s4,off,64);
        }
        if (seg == 0 && row < jn) {
            float inv = 1.f / fmaxf(sqrtf(ss), 1e-12f);
            srawT[row][0]=s0*inv; srawT[row][1]=s1*inv; srawT[row][2]=s2*inv;
            srawT[row][3]=s3*inv; srawT[row][4]=s4*inv;
        }
    }
    __syncthreads();

    // phase 2: per-c max + exp-sum over 16-row groups
    {
        int wave = t >> 6, lane = t & 63;
        bool act = (wave == 0) || (wave == 1 && lane < 16);
        if (act) {
            int c = (wave == 0) ? (lane >> 4) : 4;
            int row = lane & 15;
            float v = (row < jn) ? srawT[row][c] : -1e30f;
            float m = v;
#pragma unroll
            for (int off = 1; off < 16; off <<= 1) m = fmaxf(m, __shfl_xor(m,off,64));
            float e = (row < jn) ? expf(v - m) : 0.f;
            float s = e;
#pragma unroll
            for (int off = 1; off < 16; off <<= 1) s += __shfl_xor(s,off,64);
            if (row == 0) msum[(size_t)(chunk*B_+b)*C_ + c] = make_float2(m, s);
            if (row < jn) srawT[row][c] = e;
        }
    }
    __syncthreads();

    // phase 3: weighted partials from LDS (conflict-even columns)
    if (t < 128) {
        float acc[5][4] = {};
        const float* base = stex + t*4 + ((t>>3)<<2);
        for (int jj = 0; jj < jn; ++jj) {
            float4 v  = *(const float4*)(base + jj*576);
            float4 wA = *(const float4*)(&srawT[jj][0]);   // c0..c3
            float  wB = srawT[jj][4];
            acc[0][0]+=v.x*wA.x; acc[0][1]+=v.y*wA.x; acc[0][2]+=v.z*wA.x; acc[0][3]+=v.w*wA.x;
            acc[1][0]+=v.x*wA.y; acc[1][1]+=v.y*wA.y; acc[1][2]+=v.z*wA.y; acc[1][3]+=v.w*wA.y;
            acc[2][0]+=v.x*wA.z; acc[2][1]+=v.y*wA.z; acc[2][2]+=v.z*wA.z; acc[2][3]+=v.w*wA.z;
            acc[3][0]+=v.x*wA.w; acc[3][1]+=v.y*wA.w; acc[3][2]+=v.z*wA.w; acc[3][3]+=v.w*wA.w;
            acc[4][0]+=v.x*wB;   acc[4][1]+=v.y*wB;   acc[4][2]+=v.z*wB;   acc[4][3]+=v.w*wB;
        }
        size_t pb = ((size_t)(chunk*B_+b)*C_)*D_ + t*4;
#pragma unroll
        for (int c = 0; c < C_; ++c) {
            float4 o = make_float4(acc[c][0], acc[c][1], acc[c][2], acc[c][3]);
            *(float4*)(part + pb + (size_t)c*D_) = o;
        }
    }
}

// K4b: per-(b,c) global softmax constants -> wts[ch][bc] = e^{m_ch-mg}/denom
__global__ void k_fix(const float2* __restrict__ msum, float* __restrict__ wts) {
    int bc = threadIdx.x;                // 1 block, 160 active
    if (bc >= B_*C_) return;
    int b = bc / C_, c = bc - b*C_;
    float mg = -1e30f;
    for (int ch = 0; ch < NCHA_; ++ch) mg = fmaxf(mg, msum[(size_t)(ch*B_+b)*C_ + c].x);
    float denom = 0.f;
    for (int ch = 0; ch < NCHA_; ++ch) {
        float2 v = msum[(size_t)(ch*B_+b)*C_ + c];
        denom += v.y * expf(v.x - mg);
    }
    float invd = 1.f / denom;
    for (int ch = 0; ch < NCHA_; ++ch) {
        float2 v = msum[(size_t)(ch*B_+b)*C_ + c];
        wts[ch*(B_*C_) + bc] = expf(v.x - mg) * invd;
    }
}

// K4c: fused[bc][d] = (sum_ch part[ch][bc][d] * wts[ch][bc]) * eot[b][d]
// grid 320 x 256, fully coalesced; bc uniform per block -> wts scalar loads.
__global__ void k_reduce(const float* __restrict__ part, const float* __restrict__ wts,
                         const float* __restrict__ eot, float* __restrict__ fused) {
    int idx = blockIdx.x*256 + threadIdx.x;   // < B*C*D = 81920
    int bc = idx >> 9; int d = idx & (D_-1); int b = bc / C_;
    float s = 0.f;
#pragma unroll 2
    for (int ch = 0; ch < NCHA_; ++ch)
        s += part[(size_t)ch*(B_*C_*D_) + idx] * wts[ch*(B_*C_) + bc];
    fused[idx] = s * eot[b*D_ + d];
}

// K5: fq + TargetNet per (b,c) block (chunk loop removed).
__global__ void k_fq_target(const float* __restrict__ fused,
                            const float* __restrict__ qw, const float* __restrict__ qb,
                            const float* __restrict__ g1w, const float* __restrict__ g2w,
                            const float* __restrict__ g3w, const float* __restrict__ g4w,
                            const float* __restrict__ fcb, float* __restrict__ out) {
    int bc = blockIdx.x; int b = bc / C_; int c = bc - b*C_; (void)b;
    __shared__ float sf[D_];
    __shared__ float sa[224], sb[112];
    int t = threadIdx.x;                 // 256

    sf[t]     = fused[(size_t)bc*D_ + t];
    sf[t+256] = fused[(size_t)bc*D_ + t + 256];
    __syncthreads();

    if (t < 224) {
        const float4* w4 = (const float4*)(qw + (size_t)t*D_);
        const float4* s4 = (const float4*)sf;
        float acc = 0.f;
#pragma unroll 4
        for (int i = 0; i < 128; ++i) acc += dot4(s4[i], w4[i]);
        sa[t] = acc + qb[t];
    }
    __syncthreads();

    if (t < 112) {
        const float* w = g1w + (size_t)c*25088 + t*224;
        float s = fcb[c*112 + t];
        for (int k = 0; k < 224; ++k) s += w[k]*sa[k];
        sb[t] = 1.f/(1.f+expf(-s));
    }
    __syncthreads();
    if (t < 56) {
        const float* w = g2w + (size_t)c*6272 + t*112;
        float s = fcb[560 + c*56 + t];
        for (int k = 0; k < 112; ++k) s += w[k]*sb[k];
        sa[t] = 1.f/(1.f+expf(-s));
    }
    __syncthreads();
    if (t < 28) {
        const float* w = g3w + (size_t)c*1568 + t*56;
        float s = fcb[840 + c*28 + t];
        for (int k = 0; k < 56; ++k) s += w[k]*sa[k];
        sb[t] = 1.f/(1.f+expf(-s));
    }
    __syncthreads();
    if (t < 14) {
        const float* w = g4w + (size_t)c*392 + t*28;
        float s = fcb[980 + c*14 + t];
        for (int k = 0; k < 28; ++k) s += w[k]*sb[k];
        sa[t] = 1.f/(1.f+expf(-s));
    }
    __syncthreads();
    if (t == 0) {
        float s = fcb[1120 + c];
        for (int p = 0; p < 14; ++p) s += sa[p]*fcb[1050 + c*14 + p];
        out[b*C_ + c] = s;
    }
}

// K6: convs + (on blockIdx.x==0) pooled + hypernet fc biases.
__global__ void k_conv(const float* __restrict__ cm,
                       const float* __restrict__ w1, const float* __restrict__ bb1,
                       const float* __restrict__ w2, const float* __restrict__ bb2,
                       const float* __restrict__ w3, const float* __restrict__ bb3,
                       const float* __restrict__ w4, const float* __restrict__ bb4,
                       float* __restrict__ o1, float* __restrict__ o2,
                       float* __restrict__ o3, float* __restrict__ o4,
                       const float* __restrict__ w1b, const float* __restrict__ b1b,
                       const float* __restrict__ w2b, const float* __restrict__ b2b,
                       const float* __restrict__ w3b, const float* __restrict__ b3b,
                       const float* __restrict__ w4b, const float* __restrict__ b4b,
                       const float* __restrict__ w5w, const float* __restrict__ b5w,
                       const float* __restrict__ w5b, const float* __restrict__ b5b,
                       float* __restrict__ fcb) {
    __shared__ float im[112*108];
    __shared__ float sp[112];
    int c = blockIdx.y;
    int t = threadIdx.x;
    for (int i = t; i < 112*108; i += 256) im[i] = 0.f;
    __syncthreads();
    const float* cmc = cm + c*5488;
    for (int i = t; i < 112*49; i += 256) {
        int ch = i / 49, yx = i - ch*49;
        int y = yx / 7, x = yx - y*7;
        im[ch*108 + (y+1)*12 + (x+1)] = cmc[i];
    }
    __syncthreads();

    int oy  = blockIdx.x*64 + (t >> 2);
    int chq = t & 3;
    if (oy < 4760) {
        int o_comb = oy / 7, y = oy - o_comb*7;
        const float* w; const float* bias; float* outp; int o;
        if      (o_comb < 512) { w=w1; bias=bb1; outp=o1 + (size_t)c*512*49; o=o_comb; }
        else if (o_comb < 640) { w=w2; bias=bb2; outp=o2 + (size_t)c*128*49; o=o_comb-512; }
        else if (o_comb < 672) { w=w3; bias=bb3; outp=o3 + (size_t)c*32*49;  o=o_comb-640; }
        else                   { w=w4; bias=bb4; outp=o4 + (size_t)c*8*49;   o=o_comb-672; }

        float ac0=0,ac1=0,ac2=0,ac3=0,ac4=0,ac5=0,ac6=0;
        const float* wbase = w + ((size_t)o*112 + chq*28)*9;
        const float* imc   = im + (chq*28)*108 + y*12;
#pragma unroll 2
        for (int ch = 0; ch < 28; ++ch) {
            const float* wk = wbase + ch*9;
            const float* ii = imc + ch*108;
            float w0=wk[0],w1_=wk[1],w2_=wk[2],w3_=wk[3],w4_=wk[4],w5_=wk[5],w6_=wk[6],w7_=wk[7],w8_=wk[8];
#pragma unroll
            for (int ky = 0; ky < 3; ++ky) {
                const float* row = ii + ky*12;
                float4 ra = *(const float4*)(row);
                float4 rb = *(const float4*)(row + 4);
                float  rc = row[8];
                float r0=ra.x,r1=ra.y,r2=ra.z,r3=ra.w,r4=rb.x,r5=rb.y,r6=rb.z,r7=rb.w,r8=rc;
                float wk0 = (ky==0)?w0:((ky==1)?w3_:w6_);
                float wk1 = (ky==0)?w1_:((ky==1)?w4_:w7_);
                float wk2 = (ky==0)?w2_:((ky==1)?w5_:w8_);
                ac0 += r0*wk0 + r1*wk1 + r2*wk2;
                ac1 += r1*wk0 + r2*wk1 + r3*wk2;
                ac2 += r2*wk0 + r3*wk1 + r4*wk2;
                ac3 += r3*wk0 + r4*wk1 + r5*wk2;
                ac4 += r4*wk0 + r5*wk1 + r6*wk2;
                ac5 += r5*wk0 + r6*wk1 + r7*wk2;
                ac6 += r6*wk0 + r7*wk1 + r8*wk2;
            }
        }
        ac0 += __shfl_xor(ac0,1,64); ac0 += __shfl_xor(ac0,2,64);
        ac1 += __shfl_xor(ac1,1,64); ac1 += __shfl_xor(ac1,2,64);
        ac2 += __shfl_xor(ac2,1,64); ac2 += __shfl_xor(ac2,2,64);
        ac3 += __shfl_xor(ac3,1,64); ac3 += __shfl_xor(ac3,2,64);
        ac4 += __shfl_xor(ac4,1,64); ac4 += __shfl_xor(ac4,2,64);
        ac5 += __shfl_xor(ac5,1,64); ac5 += __shfl_xor(ac5,2,64);
        ac6 += __shfl_xor(ac6,1,64); ac6 += __shfl_xor(ac6,2,64);
        if (chq == 0) {
            float bo = bias[o];
            float* dst = outp + o*49 + y*7;
            dst[0]=ac0+bo; dst[1]=ac1+bo; dst[2]=ac2+bo; dst[3]=ac3+bo;
            dst[4]=ac4+bo; dst[5]=ac5+bo; dst[6]=ac6+bo;
        }
    }

    if (blockIdx.x == 0) {
        if (t < 112) {
            const float* p = im + t*108;
            float s = 0.f;
            for (int k = 0; k < 108; ++k) s += p[k];
            sp[t] = s * (1.f/49.f);
        }
        __syncthreads();
        if (t < 225) {
            int rel = t;
            const float* w; const float* bb; int nout; int base;
            if      (rel < 112) {            w=w1b; bb=b1b; nout=112; base=0; }
            else if (rel < 168) { rel-=112;  w=w2b; bb=b2b; nout=56;  base=560; }
            else if (rel < 196) { rel-=168;  w=w3b; bb=b3b; nout=28;  base=840; }
            else if (rel < 210) { rel-=196;  w=w4b; bb=b4b; nout=14;  base=980; }
            else if (rel < 224) { rel-=210;  w=w5w; bb=b5w; nout=14;  base=1050; }
            else                { rel-=224;  w=w5b; bb=b5b; nout=1;   base=1120; }
            float s = bb[rel];
            const float* wr = w + rel*112;
            for (int i = 0; i < 112; ++i) s += sp[i]*wr[i];
            fcb[base + c*nout + rel] = s;
        }
    }
}

extern "C" void kernel_launch(void* const* d_in, const int* in_sizes, int n_in,
                              void* d_out, int out_size, void* d_ws, size_t ws_size,
                              hipStream_t stream) {
    (void)in_sizes; (void)n_in; (void)out_size; (void)ws_size;
    const float* tex   = (const float*)d_in[0];
    const float* fp    = (const float*)d_in[1];
    const float* eot   = (const float*)d_in[2];
    const float* fcond = (const float*)d_in[3];
    const float* qw    = (const float*)d_in[4];
    const float* qb    = (const float*)d_in[5];
    const float* cw    = (const float*)d_in[6];
    const float* cb    = (const float*)d_in[7];
    const float* w1c   = (const float*)d_in[8];  const float* b1c = (const float*)d_in[9];
    const float* w2c   = (const float*)d_in[10]; const float* b2c = (const float*)d_in[11];
    const float* w3c   = (const float*)d_in[12]; const float* b3c = (const float*)d_in[13];
    const float* w4c   = (const float*)d_in[14]; const float* b4c = (const float*)d_in[15];
    const float* f1bw  = (const float*)d_in[16]; const float* f1bb = (const float*)d_in[17];
    const float* f2bw  = (const float*)d_in[18]; const float* f2bb = (const float*)d_in[19];
    const float* f3bw  = (const float*)d_in[20]; const float* f3bb = (const float*)d_in[21];
    const float* f4bw  = (const float*)d_in[22]; const float* f4bb = (const float*)d_in[23];
    const float* f5ww  = (const float*)d_in[24]; const float* f5wb = (const float*)d_in[25];
    const float* f5bw  = (const float*)d_in[26]; const float* f5bb = (const float*)d_in[27];
    float* out = (float*)d_out;

    float* ws     = (float*)d_ws;
    float* Qb     = ws;                          // 81920
    float* part   = Qb + 81920;                  // 74*32*5*512 = 6062080
    float* msv    = part + 6062080;              // 74*160*2 = 23680
    float* wts    = msv + 23680;                 // 74*160 = 11840
    float* fusedb = wts + 11840;                 // 81920
    float* cm     = fusedb + 81920;              // 27440
    float* g1w    = cm + 27440;                  // 125440
    float* g2w    = g1w + 125440;                // 31360
    float* g3w    = g2w + 31360;                 // 7840
    float* g4w    = g3w + 7840;                  // 1960
    float* fcb    = g4w + 1960;                  // 1125
    float* fn     = fcb + 1125;                  // 2560
    float* swl    = fn + 2560;                   // 12320

    k_setup<<<1373, 256, 0, stream>>>(fcond, cw, cb, cm, fn, out + B_*C_);
    k_sim<<<77, 256, 0, stream>>>(fp, fn, swl);
    k_Q<<<dim3(2, B_), 256, 0, stream>>>(fp, swl, Qb);
    k_conv<<<dim3(75, C_), 256, 0, stream>>>(cm, w1c, b1c, w2c, b2c, w3c, b3c, w4c, b4c,
                                             g1w, g2w, g3w, g4w,
                                             f1bw, f1bb, f2bw, f2bb, f3bw, f3bb,
                                             f4bw, f4bb, f5ww, f5wb, f5bw, f5bb, fcb);
    k_attn<<<dim3(NCHA_, B_), 256, 0, stream>>>(tex, Qb, part, (float2*)msv);
    k_fix<<<1, 192, 0, stream>>>((const float2*)msv, wts);
    k_reduce<<<(B_*C_*D_)/256, 256, 0, stream>>>(part, wts, eot, fusedb);
    k_fq_target<<<B_*C_, 256, 0, stream>>>(fusedb, qw, qb,
                                           g1w, g2w, g3w, g4w, fcb, out);
}

// Round 11
// 142.243 us; speedup vs baseline: 1.0768x; 1.0768x over previous
//
#include <hip/hip_runtime.h>
#include <hip/hip_bf16.h>
#include <math.h>

#define B_   32
#define J_   1182      // V*P = 6*197
#define D_   512
#define L_   77
#define C_   5
#define JCA_ 16        // j-rows per chunk
#define NCHB_ 24       // attention blocks_x; block bx handles chunks bx, bx+24, ...
#define NCH_TOT_ 74    // ceil(1182/16)

__device__ __forceinline__ float dot4(float4 a, float4 b) {
    return a.x*b.x + a.y*b.y + a.z*b.z + a.w*b.w;
}

__device__ __forceinline__ float wave_sum(float v) {
#pragma unroll
    for (int off = 32; off > 0; off >>= 1) v += __shfl_xor(v, off, 64);
    return v;
}

// K1: blocks 0..1371: cond_maps (o-major, wave per o, 5 conditions per weight read)
//     block 1372: fn normalize -> fn global + loss_dis -> loss_out
__global__ void k_setup(const float* __restrict__ fc, const float* __restrict__ cw,
                        const float* __restrict__ cb, float* __restrict__ cm,
                        float* __restrict__ fn, float* __restrict__ loss_out) {
    __shared__ float sfc[C_*D_];
    int t = threadIdx.x;
    for (int i = t; i < C_*D_; i += 256) sfc[i] = fc[i];
    __syncthreads();
    int wave = t >> 6, lane = t & 63;

    if (blockIdx.x == 1372) {
        for (int c = wave; c < C_; c += 4) {
            float ss = 0.f;
            for (int d = lane; d < D_; d += 64) { float v = sfc[c*D_+d]; ss += v*v; }
            ss = wave_sum(ss);
            float inv = 1.f / fmaxf(sqrtf(ss), 1e-12f);
            for (int d = lane; d < D_; d += 64) sfc[c*D_+d] *= inv;
        }
        __syncthreads();
        for (int i = t; i < C_*D_; i += 256) fn[i] = sfc[i];
        if (wave == 0) {
            float acc = 0.f;
            for (int i = 0; i < C_; ++i)
                for (int j = i+1; j < C_; ++j) {
                    float p = 0.f;
                    for (int d = lane; d < D_; d += 64) p += sfc[i*D_+d]*sfc[j*D_+d];
                    p = wave_sum(p);
                    acc += fmaxf(p, 0.f);
                }
            if (lane == 0) *loss_out = acc * (1.f/10.f);
        }
        return;
    }

    int o = blockIdx.x*4 + wave;         // < 5488
    const float4* w4 = (const float4*)(cw + (size_t)o*D_);
    float4 wa = w4[lane], wb = w4[lane+64];
    float bias = cb[o];
    float keep = 0.f;
#pragma unroll
    for (int c = 0; c < C_; ++c) {
        const float4* f4 = (const float4*)(sfc + c*D_);
        float s = dot4(wa, f4[lane]) + dot4(wb, f4[lane+64]);
        s = wave_sum(s);
        if (lane == c) keep = s;
    }
    if (lane < C_) cm[lane*5488 + o] = keep + bias;
}

// K2: 8 threads per (b,l) row (seg of 64 floats each), 3-level shuffle reduce.
// swl[b,c,l] = (fp[b,l]·fn[c]) / ||fp[b,l]||^2
__global__ void k_sim(const float* __restrict__ fp, const float* __restrict__ fn,
                      float* __restrict__ swl) {
    int t = threadIdx.x;                 // 256 -> 32 rows/block
    int row = t >> 3, seg = t & 7;
    int bl = blockIdx.x*32 + row;        // grid 77 -> exactly 2464 rows
    int b = bl / L_, l = bl - b*L_;
    const float4* p4 = ((const float4*)(fp + (size_t)bl*D_)) + seg*16;
    const float4* f4 = ((const float4*)fn) + seg*16;   // [c*128 + k]
    float ss=0.f, s0=0.f, s1=0.f, s2=0.f, s3=0.f, s4=0.f;
#pragma unroll 4
    for (int k = 0; k < 16; ++k) {
        float4 v = p4[k];
        ss += dot4(v, v);
        s0 += dot4(v, f4[k]);
        s1 += dot4(v, f4[128+k]);
        s2 += dot4(v, f4[256+k]);
        s3 += dot4(v, f4[384+k]);
        s4 += dot4(v, f4[512+k]);
    }
#pragma unroll
    for (int off = 1; off < 8; off <<= 1) {
        ss += __shfl_xor(ss,off,64);
        s0 += __shfl_xor(s0,off,64); s1 += __shfl_xor(s1,off,64);
        s2 += __shfl_xor(s2,off,64); s3 += __shfl_xor(s3,off,64);
        s4 += __shfl_xor(s4,off,64);
    }
    if (seg == 0) {
        float inv = 1.f / fmaxf(sqrtf(ss), 1e-12f);
        float inv2 = inv*inv;
        swl[((size_t)(b*C_+0))*L_ + l] = s0*inv2;
        swl[((size_t)(b*C_+1))*L_ + l] = s1*inv2;
        swl[((size_t)(b*C_+2))*L_ + l] = s2*inv2;
        swl[((size_t)(b*C_+3))*L_ + l] = s3*inv2;
        swl[((size_t)(b*C_+4))*L_ + l] = s4*inv2;
    }
}

// K3: Q[b,c,d] = sum_l swl[b,c,l] * fp[b,l,d]   grid (2, B_), 256 thr, d per thread
__global__ void k_Q(const float* __restrict__ fp, const float* __restrict__ swl,
                    float* __restrict__ Q) {
    __shared__ float sw[C_][80];
    int b = blockIdx.y;
    int t = threadIdx.x;
    for (int i = t; i < C_*L_; i += 256) { int c = i/L_, l = i - c*L_; sw[c][l] = swl[((size_t)(b*C_+c))*L_ + l]; }
    __syncthreads();
    int d = blockIdx.x*256 + t;
    float a0=0.f, a1=0.f, a2=0.f, a3=0.f, a4=0.f;
    const float* f = fp + (size_t)b*L_*D_ + d;
    for (int l = 0; l < L_; ++l) {
        float v = f[(size_t)l*D_];
        a0 += sw[0][l]*v; a1 += sw[1][l]*v; a2 += sw[2][l]*v;
        a3 += sw[3][l]*v; a4 += sw[4][l]*v;
    }
    Q[(size_t)(b*C_+0)*D_ + d] = a0;
    Q[(size_t)(b*C_+1)*D_ + d] = a1;
    Q[(size_t)(b*C_+2)*D_ + d] = a2;
    Q[(size_t)(b*C_+3)*D_ + d] = a3;
    Q[(size_t)(b*C_+4)*D_ + d] = a4;
}

// K4: multi-chunk flash attention. grid (NCHB_, B_), 256 thr.
// Block bx handles chunks bx, bx+24, ... with online softmax accumulation.
// Q staged ONCE per block; next chunk prefetched to registers during compute.
// LDS: row stride 576 words; float4 col4 -> word 4*col4 + 4*(col4>>3).
__global__ void k_attn(const float* __restrict__ tex, const float* __restrict__ Q,
                       float* __restrict__ part, float2* __restrict__ msum) {
    __shared__ float stex[JCA_*576];     // 36864 B
    __shared__ float sq[C_*576];         // 11520 B
    __shared__ float srawT[JCA_][8];
    __shared__ float sms[C_][2];         // running (m, s)
    __shared__ float sfac[C_];           // per-chunk acc rescale factor
    int bx = blockIdx.x, b = blockIdx.y;
    int t = threadIdx.x;                 // 256
    int row = t >> 4, seg = t & 15;

    // stage Q once
    {
        const float4* q4 = (const float4*)(Q + (size_t)b*C_*D_);
        for (int i = t; i < C_*128; i += 256) {
            int c = i >> 7, col4 = i & 127;
            *(float4*)(sq + c*576 + col4*4 + ((col4>>3)<<2)) = q4[i];
        }
        if (t < C_) { sms[t][0] = -1e30f; sms[t][1] = 0.f; }
    }

    int nch = (NCH_TOT_ - 1 - bx)/NCHB_ + 1;     // 4 for bx<2, else 3
    float4 v[8];
    float acc[5][4] = {};

    // prefetch chunk 0
    {
        int j0 = bx*JCA_;
        int jn = min(JCA_, J_ - j0);
        const float4* t4 = (const float4*)(tex + ((size_t)(b*J_ + j0))*D_);
#pragma unroll
        for (int n = 0; n < 8; ++n) {
            int i = n*256 + t;
            v[n] = ((i >> 7) < jn) ? t4[i] : make_float4(0.f,0.f,0.f,0.f);
        }
    }

    for (int it = 0; it < nch; ++it) {
        int ch = bx + it*NCHB_;
        int jn = min(JCA_, J_ - ch*JCA_);

        // write prefetched regs -> LDS (swizzled)
#pragma unroll
        for (int n = 0; n < 8; ++n) {
            int i = n*256 + t;
            int r = i >> 7, col4 = i & 127;
            *(float4*)(stex + r*576 + col4*4 + ((col4>>3)<<2)) = v[n];
        }
        __syncthreads();

        // prefetch next chunk into regs (overlaps with phases 1-3)
        if (it+1 < nch) {
            int j0n = (bx + (it+1)*NCHB_)*JCA_;
            int jnn = min(JCA_, J_ - j0n);
            const float4* t4 = (const float4*)(tex + ((size_t)(b*J_ + j0n))*D_);
#pragma unroll
            for (int n = 0; n < 8; ++n) {
                int i = n*256 + t;
                v[n] = ((i >> 7) < jnn) ? t4[i] : make_float4(0.f,0.f,0.f,0.f);
            }
        }

        // phase 1: scores from LDS
        {
            const float* sr = stex + row*576;
            float ss=0.f, s0=0.f, s1=0.f, s2=0.f, s3=0.f, s4=0.f;
#pragma unroll
            for (int k = 0; k < 8; ++k) {
                int col4 = seg*8 + k;
                int wa = col4*4 + ((col4>>3)<<2);
                float4 vv = *(const float4*)(sr + wa);
                ss += dot4(vv, vv);
                s0 += dot4(vv, *(const float4*)(sq +          wa));
                s1 += dot4(vv, *(const float4*)(sq +   576 + wa));
                s2 += dot4(vv, *(const float4*)(sq + 2*576 + wa));
                s3 += dot4(vv, *(const float4*)(sq + 3*576 + wa));
                s4 += dot4(vv, *(const float4*)(sq + 4*576 + wa));
            }
#pragma unroll
            for (int off = 1; off < 16; off <<= 1) {
                ss += __shfl_xor(ss,off,64);
                s0 += __shfl_xor(s0,off,64); s1 += __shfl_xor(s1,off,64);
                s2 += __shfl_xor(s2,off,64); s3 += __shfl_xor(s3,off,64);
                s4 += __shfl_xor(s4,off,64);
            }
            if (seg == 0 && row < jn) {
                float inv = 1.f / fmaxf(sqrtf(ss), 1e-12f);
                srawT[row][0]=s0*inv; srawT[row][1]=s1*inv; srawT[row][2]=s2*inv;
                srawT[row][3]=s3*inv; srawT[row][4]=s4*inv;
            }
        }
        __syncthreads();

        // phase 2: per-c chunk max/sum (16-lane groups) + online update
        {
            int wave = t >> 6, lane = t & 63;
            bool act = (wave == 0) || (wave == 1 && lane < 16);
            if (act) {
                int c = (wave == 0) ? (lane >> 4) : 4;
                int r2 = lane & 15;
                float val = (r2 < jn) ? srawT[r2][c] : -1e30f;
                float m = val;
#pragma unroll
                for (int off = 1; off < 16; off <<= 1) m = fmaxf(m, __shfl_xor(m,off,64));
                float e = (r2 < jn) ? expf(val - m) : 0.f;
                float s = e;
#pragma unroll
                for (int off = 1; off < 16; off <<= 1) s += __shfl_xor(s,off,64);
                float m_run = sms[c][0], s_run = sms[c][1];
                float m_new = fmaxf(m_run, m);
                float f_acc = expf(m_run - m_new);
                float f_ch  = expf(m - m_new);
                if (r2 == 0) {
                    sms[c][0] = m_new;
                    sms[c][1] = s_run*f_acc + s*f_ch;
                    sfac[c]   = f_acc;
                }
                if (r2 < jn) srawT[r2][c] = e * f_ch;
            }
        }
        __syncthreads();

        // phase 3: rescale acc + accumulate this chunk
        if (t < 128) {
            float f0=sfac[0], f1=sfac[1], f2=sfac[2], f3=sfac[3], f4=sfac[4];
#pragma unroll
            for (int k = 0; k < 4; ++k) {
                acc[0][k]*=f0; acc[1][k]*=f1; acc[2][k]*=f2; acc[3][k]*=f3; acc[4][k]*=f4;
            }
            const float* base = stex + t*4 + ((t>>3)<<2);
            for (int jj = 0; jj < jn; ++jj) {
                float4 vv = *(const float4*)(base + jj*576);
                float4 wA = *(const float4*)(&srawT[jj][0]);
                float  wB = srawT[jj][4];
                acc[0][0]+=vv.x*wA.x; acc[0][1]+=vv.y*wA.x; acc[0][2]+=vv.z*wA.x; acc[0][3]+=vv.w*wA.x;
                acc[1][0]+=vv.x*wA.y; acc[1][1]+=vv.y*wA.y; acc[1][2]+=vv.z*wA.y; acc[1][3]+=vv.w*wA.y;
                acc[2][0]+=vv.x*wA.z; acc[2][1]+=vv.y*wA.z; acc[2][2]+=vv.z*wA.z; acc[2][3]+=vv.w*wA.z;
                acc[3][0]+=vv.x*wA.w; acc[3][1]+=vv.y*wA.w; acc[3][2]+=vv.z*wA.w; acc[3][3]+=vv.w*wA.w;
                acc[4][0]+=vv.x*wB;   acc[4][1]+=vv.y*wB;   acc[4][2]+=vv.z*wB;   acc[4][3]+=vv.w*wB;
            }
        }
        __syncthreads();   // stex free for next chunk's write
    }

    // epilogue
    if (t < 128) {
        size_t pb = ((size_t)(bx*B_+b)*C_)*D_ + t*4;
#pragma unroll
        for (int c = 0; c < C_; ++c) {
            float4 o = make_float4(acc[c][0], acc[c][1], acc[c][2], acc[c][3]);
            *(float4*)(part + pb + (size_t)c*D_) = o;
        }
    }
    if (t < C_) msum[(size_t)(bx*B_+b)*C_ + t] = make_float2(sms[t][0], sms[t][1]);
}

// K4b: fused[bc][d] = (sum_bx part[bx][bc][d] * w_bx) * eot[b][d]
// grid 320 x 256; bc uniform per block; fixup computed redundantly per thread
// (24 broadcast msum loads); w[] fully unrolled -> registers.
__global__ void k_reduce(const float* __restrict__ part, const float2* __restrict__ msum,
                         const float* __restrict__ eot, float* __restrict__ fused) {
    int idx = blockIdx.x*256 + threadIdx.x;   // < B*C*D = 81920
    int bc = idx >> 9; int d = idx & (D_-1); int b = bc / C_;
    float mg = -1e30f;
#pragma unroll
    for (int ch = 0; ch < NCHB_; ++ch) mg = fmaxf(mg, msum[ch*(B_*C_) + bc].x);
    float denom = 0.f;
#pragma unroll
    for (int ch = 0; ch < NCHB_; ++ch) {
        float2 v = msum[ch*(B_*C_) + bc];
        denom += v.y * expf(v.x - mg);
    }
    float invd = 1.f / denom;
    float w[NCHB_];
#pragma unroll
    for (int ch = 0; ch < NCHB_; ++ch)
        w[ch] = expf(msum[ch*(B_*C_) + bc].x - mg) * invd;
    float s = 0.f;
#pragma unroll
    for (int ch = 0; ch < NCHB_; ++ch)
        s += part[(size_t)ch*(B_*C_*D_) + idx] * w[ch];
    fused[idx] = s * eot[b*D_ + d];
}

// K5: fq + TargetNet per (b,c) block.
__global__ void k_fq_target(const float* __restrict__ fused,
                            const float* __restrict__ qw, const float* __restrict__ qb,
                            const float* __restrict__ g1w, const float* __restrict__ g2w,
                            const float* __restrict__ g3w, const float* __restrict__ g4w,
                            const float* __restrict__ fcb, float* __restrict__ out) {
    int bc = blockIdx.x; int b = bc / C_; int c = bc - b*C_;
    __shared__ float sf[D_];
    __shared__ float sa[224], sb[112];
    int t = threadIdx.x;                 // 256

    sf[t]     = fused[(size_t)bc*D_ + t];
    sf[t+256] = fused[(size_t)bc*D_ + t + 256];
    __syncthreads();

    if (t < 224) {
        const float4* w4 = (const float4*)(qw + (size_t)t*D_);
        const float4* s4 = (const float4*)sf;
        float acc = 0.f;
#pragma unroll 4
        for (int i = 0; i < 128; ++i) acc += dot4(s4[i], w4[i]);
        sa[t] = acc + qb[t];
    }
    __syncthreads();

    if (t < 112) {
        const float* w = g1w + (size_t)c*25088 + t*224;
        float s = fcb[c*112 + t];
        for (int k = 0; k < 224; ++k) s += w[k]*sa[k];
        sb[t] = 1.f/(1.f+expf(-s));
    }
    __syncthreads();
    if (t < 56) {
        const float* w = g2w + (size_t)c*6272 + t*112;
        float s = fcb[560 + c*56 + t];
        for (int k = 0; k < 112; ++k) s += w[k]*sb[k];
        sa[t] = 1.f/(1.f+expf(-s));
    }
    __syncthreads();
    if (t < 28) {
        const float* w = g3w + (size_t)c*1568 + t*56;
        float s = fcb[840 + c*28 + t];
        for (int k = 0; k < 56; ++k) s += w[k]*sa[k];
        sb[t] = 1.f/(1.f+expf(-s));
    }
    __syncthreads();
    if (t < 14) {
        const float* w = g4w + (size_t)c*392 + t*28;
        float s = fcb[980 + c*14 + t];
        for (int k = 0; k < 28; ++k) s += w[k]*sb[k];
        sa[t] = 1.f/(1.f+expf(-s));
    }
    __syncthreads();
    if (t == 0) {
        float s = fcb[1120 + c];
        for (int p = 0; p < 14; ++p) s += sa[p]*fcb[1050 + c*14 + p];
        out[b*C_ + c] = s;
    }
}

// K6: convs + (on blockIdx.x==0) pooled + hypernet fc biases.
__global__ void k_conv(const float* __restrict__ cm,
                       const float* __restrict__ w1, const float* __restrict__ bb1,
                       const float* __restrict__ w2, const float* __restrict__ bb2,
                       const float* __restrict__ w3, const float* __restrict__ bb3,
                       const float* __restrict__ w4, const float* __restrict__ bb4,
                       float* __restrict__ o1, float* __restrict__ o2,
                       float* __restrict__ o3, float* __restrict__ o4,
                       const float* __restrict__ w1b, const float* __restrict__ b1b,
                       const float* __restrict__ w2b, const float* __restrict__ b2b,
                       const float* __restrict__ w3b, const float* __restrict__ b3b,
                       const float* __restrict__ w4b, const float* __restrict__ b4b,
                       const float* __restrict__ w5w, const float* __restrict__ b5w,
                       const float* __restrict__ w5b, const float* __restrict__ b5b,
                       float* __restrict__ fcb) {
    __shared__ float im[112*108];
    __shared__ float sp[112];
    int c = blockIdx.y;
    int t = threadIdx.x;
    for (int i = t; i < 112*108; i += 256) im[i] = 0.f;
    __syncthreads();
    const float* cmc = cm + c*5488;
    for (int i = t; i < 112*49; i += 256) {
        int ch = i / 49, yx = i - ch*49;
        int y = yx / 7, x = yx - y*7;
        im[ch*108 + (y+1)*12 + (x+1)] = cmc[i];
    }
    __syncthreads();

    int oy  = blockIdx.x*64 + (t >> 2);
    int chq = t & 3;
    if (oy < 4760) {
        int o_comb = oy / 7, y = oy - o_comb*7;
        const float* w; const float* bias; float* outp; int o;
        if      (o_comb < 512) { w=w1; bias=bb1; outp=o1 + (size_t)c*512*49; o=o_comb; }
        else if (o_comb < 640) { w=w2; bias=bb2; outp=o2 + (size_t)c*128*49; o=o_comb-512; }
        else if (o_comb < 672) { w=w3; bias=bb3; outp=o3 + (size_t)c*32*49;  o=o_comb-640; }
        else                   { w=w4; bias=bb4; outp=o4 + (size_t)c*8*49;   o=o_comb-672; }

        float ac0=0,ac1=0,ac2=0,ac3=0,ac4=0,ac5=0,ac6=0;
        const float* wbase = w + ((size_t)o*112 + chq*28)*9;
        const float* imc   = im + (chq*28)*108 + y*12;
#pragma unroll 2
        for (int ch = 0; ch < 28; ++ch) {
            const float* wk = wbase + ch*9;
            const float* ii = imc + ch*108;
            float w0=wk[0],w1_=wk[1],w2_=wk[2],w3_=wk[3],w4_=wk[4],w5_=wk[5],w6_=wk[6],w7_=wk[7],w8_=wk[8];
#pragma unroll
            for (int ky = 0; ky < 3; ++ky) {
                const float* row = ii + ky*12;
                float4 ra = *(const float4*)(row);
                float4 rb = *(const float4*)(row + 4);
                float  rc = row[8];
                float r0=ra.x,r1=ra.y,r2=ra.z,r3=ra.w,r4=rb.x,r5=rb.y,r6=rb.z,r7=rb.w,r8=rc;
                float wk0 = (ky==0)?w0:((ky==1)?w3_:w6_);
                float wk1 = (ky==0)?w1_:((ky==1)?w4_:w7_);
                float wk2 = (ky==0)?w2_:((ky==1)?w5_:w8_);
                ac0 += r0*wk0 + r1*wk1 + r2*wk2;
                ac1 += r1*wk0 + r2*wk1 + r3*wk2;
                ac2 += r2*wk0 + r3*wk1 + r4*wk2;
                ac3 += r3*wk0 + r4*wk1 + r5*wk2;
                ac4 += r4*wk0 + r5*wk1 + r6*wk2;
                ac5 += r5*wk0 + r6*wk1 + r7*wk2;
                ac6 += r6*wk0 + r7*wk1 + r8*wk2;
            }
        }
        ac0 += __shfl_xor(ac0,1,64); ac0 += __shfl_xor(ac0,2,64);
        ac1 += __shfl_xor(ac1,1,64); ac1 += __shfl_xor(ac1,2,64);
        ac2 += __shfl_xor(ac2,1,64); ac2 += __shfl_xor(ac2,2,64);
        ac3 += __shfl_xor(ac3,1,64); ac3 += __shfl_xor(ac3,2,64);
        ac4 += __shfl_xor(ac4,1,64); ac4 += __shfl_xor(ac4,2,64);
        ac5 += __shfl_xor(ac5,1,64); ac5 += __shfl_xor(ac5,2,64);
        ac6 += __shfl_xor(ac6,1,64); ac6 += __shfl_xor(ac6,2,64);
        if (chq == 0) {
            float bo = bias[o];
            float* dst = outp + o*49 + y*7;
            dst[0]=ac0+bo; dst[1]=ac1+bo; dst[2]=ac2+bo; dst[3]=ac3+bo;
            dst[4]=ac4+bo; dst[5]=ac5+bo; dst[6]=ac6+bo;
        }
    }

    if (blockIdx.x == 0) {
        if (t < 112) {
            const float* p = im + t*108;
            float s = 0.f;
            for (int k = 0; k < 108; ++k) s += p[k];
            sp[t] = s * (1.f/49.f);
        }
        __syncthreads();
        if (t < 225) {
            int rel = t;
            const float* w; const float* bb; int nout; int base;
            if      (rel < 112) {            w=w1b; bb=b1b; nout=112; base=0; }
            else if (rel < 168) { rel-=112;  w=w2b; bb=b2b; nout=56;  base=560; }
            else if (rel < 196) { rel-=168;  w=w3b; bb=b3b; nout=28;  base=840; }
            else if (rel < 210) { rel-=196;  w=w4b; bb=b4b; nout=14;  base=980; }
            else if (rel < 224) { rel-=210;  w=w5w; bb=b5w; nout=14;  base=1050; }
            else                { rel-=224;  w=w5b; bb=b5b; nout=1;   base=1120; }
            float s = bb[rel];
            const float* wr = w + rel*112;
            for (int i = 0; i < 112; ++i) s += sp[i]*wr[i];
            fcb[base + c*nout + rel] = s;
        }
    }
}

extern "C" void kernel_launch(void* const* d_in, const int* in_sizes, int n_in,
                              void* d_out, int out_size, void* d_ws, size_t ws_size,
                              hipStream_t stream) {
    (void)in_sizes; (void)n_in; (void)out_size; (void)ws_size;
    const float* tex   = (const float*)d_in[0];
    const float* fp    = (const float*)d_in[1];
    const float* eot   = (const float*)d_in[2];
    const float* fcond = (const float*)d_in[3];
    const float* qw    = (const float*)d_in[4];
    const float* qb    = (const float*)d_in[5];
    const float* cw    = (const float*)d_in[6];
    const float* cb    = (const float*)d_in[7];
    const float* w1c   = (const float*)d_in[8];  const float* b1c = (const float*)d_in[9];
    const float* w2c   = (const float*)d_in[10]; const float* b2c = (const float*)d_in[11];
    const float* w3c   = (const float*)d_in[12]; const float* b3c = (const float*)d_in[13];
    const float* w4c   = (const float*)d_in[14]; const float* b4c = (const float*)d_in[15];
    const float* f1bw  = (const float*)d_in[16]; const float* f1bb = (const float*)d_in[17];
    const float* f2bw  = (const float*)d_in[18]; const float* f2bb = (const float*)d_in[19];
    const float* f3bw  = (const float*)d_in[20]; const float* f3bb = (const float*)d_in[21];
    const float* f4bw  = (const float*)d_in[22]; const float* f4bb = (const float*)d_in[23];
    const float* f5ww  = (const float*)d_in[24]; const float* f5wb = (const float*)d_in[25];
    const float* f5bw  = (const float*)d_in[26]; const float* f5bb = (const float*)d_in[27];
    float* out = (float*)d_out;

    float* ws     = (float*)d_ws;
    float* Qb     = ws;                          // 81920
    float* part   = Qb + 81920;                  // 24*32*5*512 = 1966080
    float* msv    = part + 1966080;              // 24*160*2 = 7680
    float* fusedb = msv + 7680;                  // 81920
    float* cm     = fusedb + 81920;              // 27440
    float* g1w    = cm + 27440;                  // 125440
    float* g2w    = g1w + 125440;                // 31360
    float* g3w    = g2w + 31360;                 // 7840
    float* g4w    = g3w + 7840;                  // 1960
    float* fcb    = g4w + 1960;                  // 1125
    float* fn     = fcb + 1125;                  // 2560
    float* swl    = fn + 2560;                   // 12320

    k_setup<<<1373, 256, 0, stream>>>(fcond, cw, cb, cm, fn, out + B_*C_);
    k_sim<<<77, 256, 0, stream>>>(fp, fn, swl);
    k_Q<<<dim3(2, B_), 256, 0, stream>>>(fp, swl, Qb);
    k_conv<<<dim3(75, C_), 256, 0, stream>>>(cm, w1c, b1c, w2c, b2c, w3c, b3c, w4c, b4c,
                                             g1w, g2w, g3w, g4w,
                                             f1bw, f1bb, f2bw, f2bb, f3bw, f3bb,
                                             f4bw, f4bb, f5ww, f5wb, f5bw, f5bb, fcb);
    k_attn<<<dim3(NCHB_, B_), 256, 0, stream>>>(tex, Qb, part, (float2*)msv);
    k_reduce<<<(B_*C_*D_)/256, 256, 0, stream>>>(part, (const float2*)msv, eot, fusedb);
    k_fq_target<<<B_*C_, 256, 0, stream>>>(fusedb, qw, qb,
                                           g1w, g2w, g3w, g4w, fcb, out);
}

// Round 12
// 126.786 us; speedup vs baseline: 1.2081x; 1.1219x over previous
//
#include <hip/hip_runtime.h>
#include <hip/hip_bf16.h>
#include <math.h>

#define B_   32
#define J_   1182      // V*P = 6*197
#define D_   512
#define L_   77
#define C_   5
#define JC_  64        // j-chunk for ftf
#define NCH_ 19        // ceil(1182/64)

__device__ __forceinline__ float dot4(float4 a, float4 b) {
    return a.x*b.x + a.y*b.y + a.z*b.z + a.w*b.w;
}

__device__ __forceinline__ float wave_sum(float v) {
#pragma unroll
    for (int off = 32; off > 0; off >>= 1) v += __shfl_xor(v, off, 64);
    return v;
}

__device__ __forceinline__ float wave_max(float v) {
#pragma unroll
    for (int off = 32; off > 0; off >>= 1) v = fmaxf(v, __shfl_xor(v, off, 64));
    return v;
}

// K1: blocks 0..1371: cond_maps (o-major, wave per o, 5 conditions per weight read)
//     block 1372: fn normalize -> fn global + loss_dis -> loss_out
__global__ void k_setup(const float* __restrict__ fc, const float* __restrict__ cw,
                        const float* __restrict__ cb, float* __restrict__ cm,
                        float* __restrict__ fn, float* __restrict__ loss_out) {
    __shared__ float sfc[C_*D_];
    int t = threadIdx.x;
    for (int i = t; i < C_*D_; i += 256) sfc[i] = fc[i];
    __syncthreads();
    int wave = t >> 6, lane = t & 63;

    if (blockIdx.x == 1372) {
        for (int c = wave; c < C_; c += 4) {
            float ss = 0.f;
            for (int d = lane; d < D_; d += 64) { float v = sfc[c*D_+d]; ss += v*v; }
            ss = wave_sum(ss);
            float inv = 1.f / fmaxf(sqrtf(ss), 1e-12f);
            for (int d = lane; d < D_; d += 64) sfc[c*D_+d] *= inv;
        }
        __syncthreads();
        for (int i = t; i < C_*D_; i += 256) fn[i] = sfc[i];
        if (wave == 0) {
            float acc = 0.f;
            for (int i = 0; i < C_; ++i)
                for (int j = i+1; j < C_; ++j) {
                    float p = 0.f;
                    for (int d = lane; d < D_; d += 64) p += sfc[i*D_+d]*sfc[j*D_+d];
                    p = wave_sum(p);
                    acc += fmaxf(p, 0.f);
                }
            if (lane == 0) *loss_out = acc * (1.f/10.f);
        }
        return;
    }

    int o = blockIdx.x*4 + wave;         // < 5488
    const float4* w4 = (const float4*)(cw + (size_t)o*D_);
    float4 wa = w4[lane], wb = w4[lane+64];
    float bias = cb[o];
    float keep = 0.f;
#pragma unroll
    for (int c = 0; c < C_; ++c) {
        const float4* f4 = (const float4*)(sfc + c*D_);
        float s = dot4(wa, f4[lane]) + dot4(wb, f4[lane+64]);
        s = wave_sum(s);
        if (lane == c) keep = s;
    }
    if (lane < C_) cm[lane*5488 + o] = keep + bias;
}

// K2: 8 threads per (b,l) row (seg of 64 floats each), 3-level shuffle reduce.
// swl[b,c,l] = (fp[b,l]·fn[c]) / ||fp[b,l]||^2
__global__ void k_sim(const float* __restrict__ fp, const float* __restrict__ fn,
                      float* __restrict__ swl) {
    int t = threadIdx.x;                 // 256 -> 32 rows/block
    int row = t >> 3, seg = t & 7;
    int bl = blockIdx.x*32 + row;        // grid 77 -> exactly 2464 rows
    int b = bl / L_, l = bl - b*L_;
    const float4* p4 = ((const float4*)(fp + (size_t)bl*D_)) + seg*16;
    const float4* f4 = ((const float4*)fn) + seg*16;   // [c*128 + k]
    float ss=0.f, s0=0.f, s1=0.f, s2=0.f, s3=0.f, s4=0.f;
#pragma unroll 4
    for (int k = 0; k < 16; ++k) {
        float4 v = p4[k];
        ss += dot4(v, v);
        s0 += dot4(v, f4[k]);
        s1 += dot4(v, f4[128+k]);
        s2 += dot4(v, f4[256+k]);
        s3 += dot4(v, f4[384+k]);
        s4 += dot4(v, f4[512+k]);
    }
#pragma unroll
    for (int off = 1; off < 8; off <<= 1) {
        ss += __shfl_xor(ss,off,64);
        s0 += __shfl_xor(s0,off,64); s1 += __shfl_xor(s1,off,64);
        s2 += __shfl_xor(s2,off,64); s3 += __shfl_xor(s3,off,64);
        s4 += __shfl_xor(s4,off,64);
    }
    if (seg == 0) {
        float inv = 1.f / fmaxf(sqrtf(ss), 1e-12f);
        float inv2 = inv*inv;
        swl[((size_t)(b*C_+0))*L_ + l] = s0*inv2;
        swl[((size_t)(b*C_+1))*L_ + l] = s1*inv2;
        swl[((size_t)(b*C_+2))*L_ + l] = s2*inv2;
        swl[((size_t)(b*C_+3))*L_ + l] = s3*inv2;
        swl[((size_t)(b*C_+4))*L_ + l] = s4*inv2;
    }
}

// K3: Q[b,c,d] = sum_l swl[b,c,l] * fp[b,l,d]   grid (2, B_), 256 thr, d per thread
__global__ void k_Q(const float* __restrict__ fp, const float* __restrict__ swl,
                    float* __restrict__ Q) {
    __shared__ float sw[C_][80];
    int b = blockIdx.y;
    int t = threadIdx.x;
    for (int i = t; i < C_*L_; i += 256) { int c = i/L_, l = i - c*L_; sw[c][l] = swl[((size_t)(b*C_+c))*L_ + l]; }
    __syncthreads();
    int d = blockIdx.x*256 + t;
    float a0=0.f, a1=0.f, a2=0.f, a3=0.f, a4=0.f;
    const float* f = fp + (size_t)b*L_*D_ + d;
    for (int l = 0; l < L_; ++l) {
        float v = f[(size_t)l*D_];
        a0 += sw[0][l]*v; a1 += sw[1][l]*v; a2 += sw[2][l]*v;
        a3 += sw[3][l]*v; a4 += sw[4][l]*v;
    }
    Q[(size_t)(b*C_+0)*D_ + d] = a0;
    Q[(size_t)(b*C_+1)*D_ + d] = a1;
    Q[(size_t)(b*C_+2)*D_ + d] = a2;
    Q[(size_t)(b*C_+3)*D_ + d] = a3;
    Q[(size_t)(b*C_+4)*D_ + d] = a4;
}

// K4: pw_raw[b,c,j] = (1/||tex[b,j]||) * dot(tex[b,j,:], Q[b,c,:])  [tex pass #1]
// grid (37, B_), 256 thr = 32 rows x 8 segs. Q in LDS, bank-transposed
// Qs[(c*16+k)*8+seg] so the 8 segs hit 8 distinct bank-quads (conflict-free,
// row-broadcast). 3-level shuffle reduce per row. No per-block tex staging.
__global__ void k_pw(const float* __restrict__ tex, const float* __restrict__ Q,
                     float* __restrict__ pw) {
    __shared__ float4 qs[C_*128];        // 10240 B
    int b = blockIdx.y, t = threadIdx.x;
    {
        const float4* q4 = (const float4*)(Q + (size_t)b*C_*D_);
        for (int i = t; i < C_*128; i += 256) {
            int c = i >> 7, f = i & 127;
            int seg = f >> 4, k = f & 15;
            qs[(c*16 + k)*8 + seg] = q4[i];
        }
    }
    __syncthreads();
    int row = t >> 3, seg = t & 7;
    int j = blockIdx.x*32 + row;
    if (j >= J_) return;
    const float4* tp = (const float4*)(tex + ((size_t)(b*J_ + j))*D_ + seg*64);
    float ss=0.f, s0=0.f, s1=0.f, s2=0.f, s3=0.f, s4=0.f;
#pragma unroll 4
    for (int k = 0; k < 16; ++k) {
        float4 v = tp[k];
        int base = k*8 + seg;
        ss += dot4(v, v);
        s0 += dot4(v, qs[base]);
        s1 += dot4(v, qs[128 + base]);
        s2 += dot4(v, qs[256 + base]);
        s3 += dot4(v, qs[384 + base]);
        s4 += dot4(v, qs[512 + base]);
    }
#pragma unroll
    for (int off = 1; off < 8; off <<= 1) {
        ss += __shfl_xor(ss,off,64);
        s0 += __shfl_xor(s0,off,64); s1 += __shfl_xor(s1,off,64);
        s2 += __shfl_xor(s2,off,64); s3 += __shfl_xor(s3,off,64);
        s4 += __shfl_xor(s4,off,64);
    }
    if (seg == 0) {
        float inv = 1.f / fmaxf(sqrtf(ss), 1e-12f);
        pw[((size_t)(b*C_+0))*J_ + j] = s0*inv;
        pw[((size_t)(b*C_+1))*J_ + j] = s1*inv;
        pw[((size_t)(b*C_+2))*J_ + j] = s2*inv;
        pw[((size_t)(b*C_+3))*J_ + j] = s3*inv;
        pw[((size_t)(b*C_+4))*J_ + j] = s4*inv;
    }
}

// K5: softmax stats per (b,c): sms[bc] = (m, 1/sum). grid B_, 320 thr (wave per c).
__global__ void k_sm(const float* __restrict__ pw, float2* __restrict__ sms) {
    int b = blockIdx.x;
    int c = threadIdx.x >> 6, lane = threadIdx.x & 63;
    const float* row = pw + (size_t)(b*C_+c)*J_;
    float m = -1e30f;
    for (int j = lane; j < J_; j += 64) m = fmaxf(m, row[j]);
    m = wave_max(m);
    float s = 0.f;
    for (int j = lane; j < J_; j += 64) s += expf(row[j] - m);
    s = wave_sum(s);
    if (lane == 0) sms[b*C_ + c] = make_float2(m, 1.f/s);
}

// K6: ftf partials, exp applied inline from sms  [tex pass #2]
// part[chunk][b][c][d] = sum_{j in chunk} tex[b,j,d] * exp(pw-m)*invs
__global__ void k_ftf(const float* __restrict__ tex, const float* __restrict__ pwraw,
                      const float2* __restrict__ sms, float* __restrict__ part) {
    __shared__ float sw[C_][JC_];
    int chunk = blockIdx.x, b = blockIdx.y;
    int t = threadIdx.x;                 // 512
    int j0 = chunk*JC_;
    int jn = min(JC_, J_ - j0);
    if (t < C_*JC_) {
        int c = t >> 6, jj = t & 63;
        float2 ms = sms[b*C_ + c];
        sw[c][jj] = (jj < jn)
            ? expf(pwraw[((size_t)(b*C_+c))*J_ + j0 + jj] - ms.x) * ms.y
            : 0.f;
    }
    __syncthreads();
    float acc0=0.f, acc1=0.f, acc2=0.f, acc3=0.f, acc4=0.f;
    const float* tp = tex + ((size_t)b*J_ + j0)*D_ + t;
    for (int jj = 0; jj < jn; ++jj) {
        float v = tp[(size_t)jj*D_];
        acc0 += v*sw[0][jj]; acc1 += v*sw[1][jj]; acc2 += v*sw[2][jj];
        acc3 += v*sw[3][jj]; acc4 += v*sw[4][jj];
    }
    size_t base = (((size_t)chunk*B_ + b)*C_)*D_ + t;
    part[base               ] = acc0;
    part[base +   (size_t)D_] = acc1;
    part[base + 2*(size_t)D_] = acc2;
    part[base + 3*(size_t)D_] = acc3;
    part[base + 4*(size_t)D_] = acc4;
}

// K7: fused chunk-reduce + eot + fq + TargetNet per (b,c) block. No shuffles.
__global__ void k_fq_target(const float* __restrict__ part, const float* __restrict__ eot,
                            const float* __restrict__ qw, const float* __restrict__ qb,
                            const float* __restrict__ g1w, const float* __restrict__ g2w,
                            const float* __restrict__ g3w, const float* __restrict__ g4w,
                            const float* __restrict__ fcb, float* __restrict__ out) {
    int bc = blockIdx.x; int b = bc / C_; int c = bc - b*C_;
    __shared__ float sf[D_];
    __shared__ float sa[224], sb[112];
    int t = threadIdx.x;                 // 256

    float s0 = 0.f, s1 = 0.f;
    for (int ch = 0; ch < NCH_; ++ch) {
        const float* p = part + ((size_t)ch*(B_*C_) + bc)*D_;
        s0 += p[t]; s1 += p[t+256];
    }
    sf[t]     = s0 * eot[b*D_ + t];
    sf[t+256] = s1 * eot[b*D_ + t + 256];
    __syncthreads();

    if (t < 224) {
        const float4* w4 = (const float4*)(qw + (size_t)t*D_);
        const float4* s4 = (const float4*)sf;
        float acc = 0.f;
#pragma unroll 4
        for (int i = 0; i < 128; ++i) acc += dot4(s4[i], w4[i]);
        sa[t] = acc + qb[t];
    }
    __syncthreads();

    if (t < 112) {
        const float* w = g1w + (size_t)c*25088 + t*224;
        float s = fcb[c*112 + t];
        for (int k = 0; k < 224; ++k) s += w[k]*sa[k];
        sb[t] = 1.f/(1.f+expf(-s));
    }
    __syncthreads();
    if (t < 56) {
        const float* w = g2w + (size_t)c*6272 + t*112;
        float s = fcb[560 + c*56 + t];
        for (int k = 0; k < 112; ++k) s += w[k]*sb[k];
        sa[t] = 1.f/(1.f+expf(-s));
    }
    __syncthreads();
    if (t < 28) {
        const float* w = g3w + (size_t)c*1568 + t*56;
        float s = fcb[840 + c*28 + t];
        for (int k = 0; k < 56; ++k) s += w[k]*sa[k];
        sb[t] = 1.f/(1.f+expf(-s));
    }
    __syncthreads();
    if (t < 14) {
        const float* w = g4w + (size_t)c*392 + t*28;
        float s = fcb[980 + c*14 + t];
        for (int k = 0; k < 28; ++k) s += w[k]*sb[k];
        sa[t] = 1.f/(1.f+expf(-s));
    }
    __syncthreads();
    if (t == 0) {
        float s = fcb[1120 + c];
        for (int p = 0; p < 14; ++p) s += sa[p]*fcb[1050 + c*14 + p];
        out[b*C_ + c] = s;
    }
}

// K8: convs + (on blockIdx.x==0) pooled + hypernet fc biases.
__global__ void k_conv(const float* __restrict__ cm,
                       const float* __restrict__ w1, const float* __restrict__ bb1,
                       const float* __restrict__ w2, const float* __restrict__ bb2,
                       const float* __restrict__ w3, const float* __restrict__ bb3,
                       const float* __restrict__ w4, const float* __restrict__ bb4,
                       float* __restrict__ o1, float* __restrict__ o2,
                       float* __restrict__ o3, float* __restrict__ o4,
                       const float* __restrict__ w1b, const float* __restrict__ b1b,
                       const float* __restrict__ w2b, const float* __restrict__ b2b,
                       const float* __restrict__ w3b, const float* __restrict__ b3b,
                       const float* __restrict__ w4b, const float* __restrict__ b4b,
                       const float* __restrict__ w5w, const float* __restrict__ b5w,
                       const float* __restrict__ w5b, const float* __restrict__ b5b,
                       float* __restrict__ fcb) {
    __shared__ float im[112*108];
    __shared__ float sp[112];
    int c = blockIdx.y;
    int t = threadIdx.x;
    for (int i = t; i < 112*108; i += 256) im[i] = 0.f;
    __syncthreads();
    const float* cmc = cm + c*5488;
    for (int i = t; i < 112*49; i += 256) {
        int ch = i / 49, yx = i - ch*49;
        int y = yx / 7, x = yx - y*7;
        im[ch*108 + (y+1)*12 + (x+1)] = cmc[i];
    }
    __syncthreads();

    int oy  = blockIdx.x*64 + (t >> 2);
    int chq = t & 3;
    if (oy < 4760) {
        int o_comb = oy / 7, y = oy - o_comb*7;
        const float* w; const float* bias; float* outp; int o;
        if      (o_comb < 512) { w=w1; bias=bb1; outp=o1 + (size_t)c*512*49; o=o_comb; }
        else if (o_comb < 640) { w=w2; bias=bb2; outp=o2 + (size_t)c*128*49; o=o_comb-512; }
        else if (o_comb < 672) { w=w3; bias=bb3; outp=o3 + (size_t)c*32*49;  o=o_comb-640; }
        else                   { w=w4; bias=bb4; outp=o4 + (size_t)c*8*49;   o=o_comb-672; }

        float ac0=0,ac1=0,ac2=0,ac3=0,ac4=0,ac5=0,ac6=0;
        const float* wbase = w + ((size_t)o*112 + chq*28)*9;
        const float* imc   = im + (chq*28)*108 + y*12;
#pragma unroll 2
        for (int ch = 0; ch < 28; ++ch) {
            const float* wk = wbase + ch*9;
            const float* ii = imc + ch*108;
            float w0=wk[0],w1_=wk[1],w2_=wk[2],w3_=wk[3],w4_=wk[4],w5_=wk[5],w6_=wk[6],w7_=wk[7],w8_=wk[8];
#pragma unroll
            for (int ky = 0; ky < 3; ++ky) {
                const float* row = ii + ky*12;
                float4 ra = *(const float4*)(row);
                float4 rb = *(const float4*)(row + 4);
                float  rc = row[8];
                float r0=ra.x,r1=ra.y,r2=ra.z,r3=ra.w,r4=rb.x,r5=rb.y,r6=rb.z,r7=rb.w,r8=rc;
                float wk0 = (ky==0)?w0:((ky==1)?w3_:w6_);
                float wk1 = (ky==0)?w1_:((ky==1)?w4_:w7_);
                float wk2 = (ky==0)?w2_:((ky==1)?w5_:w8_);
                ac0 += r0*wk0 + r1*wk1 + r2*wk2;
                ac1 += r1*wk0 + r2*wk1 + r3*wk2;
                ac2 += r2*wk0 + r3*wk1 + r4*wk2;
                ac3 += r3*wk0 + r4*wk1 + r5*wk2;
                ac4 += r4*wk0 + r5*wk1 + r6*wk2;
                ac5 += r5*wk0 + r6*wk1 + r7*wk2;
                ac6 += r6*wk0 + r7*wk1 + r8*wk2;
            }
        }
        ac0 += __shfl_xor(ac0,1,64); ac0 += __shfl_xor(ac0,2,64);
        ac1 += __shfl_xor(ac1,1,64); ac1 += __shfl_xor(ac1,2,64);
        ac2 += __shfl_xor(ac2,1,64); ac2 += __shfl_xor(ac2,2,64);
        ac3 += __shfl_xor(ac3,1,64); ac3 += __shfl_xor(ac3,2,64);
        ac4 += __shfl_xor(ac4,1,64); ac4 += __shfl_xor(ac4,2,64);
        ac5 += __shfl_xor(ac5,1,64); ac5 += __shfl_xor(ac5,2,64);
        ac6 += __shfl_xor(ac6,1,64); ac6 += __shfl_xor(ac6,2,64);
        if (chq == 0) {
            float bo = bias[o];
            float* dst = outp + o*49 + y*7;
            dst[0]=ac0+bo; dst[1]=ac1+bo; dst[2]=ac2+bo; dst[3]=ac3+bo;
            dst[4]=ac4+bo; dst[5]=ac5+bo; dst[6]=ac6+bo;
        }
    }

    if (blockIdx.x == 0) {
        if (t < 112) {
            const float* p = im + t*108;
            float s = 0.f;
            for (int k = 0; k < 108; ++k) s += p[k];
            sp[t] = s * (1.f/49.f);
        }
        __syncthreads();
        if (t < 225) {
            int rel = t;
            const float* w; const float* bb; int nout; int base;
            if      (rel < 112) {            w=w1b; bb=b1b; nout=112; base=0; }
            else if (rel < 168) { rel-=112;  w=w2b; bb=b2b; nout=56;  base=560; }
            else if (rel < 196) { rel-=168;  w=w3b; bb=b3b; nout=28;  base=840; }
            else if (rel < 210) { rel-=196;  w=w4b; bb=b4b; nout=14;  base=980; }
            else if (rel < 224) { rel-=210;  w=w5w; bb=b5w; nout=14;  base=1050; }
            else                { rel-=224;  w=w5b; bb=b5b; nout=1;   base=1120; }
            float s = bb[rel];
            const float* wr = w + rel*112;
            for (int i = 0; i < 112; ++i) s += sp[i]*wr[i];
            fcb[base + c*nout + rel] = s;
        }
    }
}

extern "C" void kernel_launch(void* const* d_in, const int* in_sizes, int n_in,
                              void* d_out, int out_size, void* d_ws, size_t ws_size,
                              hipStream_t stream) {
    (void)in_sizes; (void)n_in; (void)out_size; (void)ws_size;
    const float* tex   = (const float*)d_in[0];
    const float* fp    = (const float*)d_in[1];
    const float* eot   = (const float*)d_in[2];
    const float* fcond = (const float*)d_in[3];
    const float* qw    = (const float*)d_in[4];
    const float* qb    = (const float*)d_in[5];
    const float* cw    = (const float*)d_in[6];
    const float* cb    = (const float*)d_in[7];
    const float* w1c   = (const float*)d_in[8];  const float* b1c = (const float*)d_in[9];
    const float* w2c   = (const float*)d_in[10]; const float* b2c = (const float*)d_in[11];
    const float* w3c   = (const float*)d_in[12]; const float* b3c = (const float*)d_in[13];
    const float* w4c   = (const float*)d_in[14]; const float* b4c = (const float*)d_in[15];
    const float* f1bw  = (const float*)d_in[16]; const float* f1bb = (const float*)d_in[17];
    const float* f2bw  = (const float*)d_in[18]; const float* f2bb = (const float*)d_in[19];
    const float* f3bw  = (const float*)d_in[20]; const float* f3bb = (const float*)d_in[21];
    const float* f4bw  = (const float*)d_in[22]; const float* f4bb = (const float*)d_in[23];
    const float* f5ww  = (const float*)d_in[24]; const float* f5wb = (const float*)d_in[25];
    const float* f5bw  = (const float*)d_in[26]; const float* f5bb = (const float*)d_in[27];
    float* out = (float*)d_out;

    float* ws     = (float*)d_ws;
    float* Qb     = ws;                          // 81920
    float* pw     = Qb + 81920;                  // 189120
    float* part   = pw + 189120;                 // 19*81920 = 1556480
    float* sms    = part + 1556480;              // 320 (float2[160], 8B-aligned)
    float* cm     = sms + 320;                   // 27440
    float* g1w    = cm + 27440;                  // 125440
    float* g2w    = g1w + 125440;                // 31360
    float* g3w    = g2w + 31360;                 // 7840
    float* g4w    = g3w + 7840;                  // 1960
    float* fcb    = g4w + 1960;                  // 1125
    float* fn     = fcb + 1125;                  // 2560
    float* swl    = fn + 2560;                   // 12320

    k_setup<<<1373, 256, 0, stream>>>(fcond, cw, cb, cm, fn, out + B_*C_);
    k_sim<<<77, 256, 0, stream>>>(fp, fn, swl);
    k_Q<<<dim3(2, B_), 256, 0, stream>>>(fp, swl, Qb);
    k_conv<<<dim3(75, C_), 256, 0, stream>>>(cm, w1c, b1c, w2c, b2c, w3c, b3c, w4c, b4c,
                                             g1w, g2w, g3w, g4w,
                                             f1bw, f1bb, f2bw, f2bb, f3bw, f3bb,
                                             f4bw, f4bb, f5ww, f5wb, f5bw, f5bb, fcb);
    k_pw<<<dim3(37, B_), 256, 0, stream>>>(tex, Qb, pw);
    k_sm<<<B_, 320, 0, stream>>>(pw, (float2*)sms);
    k_ftf<<<dim3(NCH_, B_), 512, 0, stream>>>(tex, pw, (const float2*)sms, part);
    k_fq_target<<<B_*C_, 256, 0, stream>>>(part, eot, qw, qb,
                                           g1w, g2w, g3w, g4w, fcb, out);
}